// Round 6
// baseline (259.209 us; speedup 1.0000x reference)
//
#include <hip/hip_runtime.h>
#include <hip/hip_bf16.h>

#define N_NODES 100000
#define NUM_TYPES 8
#define FACTOR 0.125f  // 1/sqrt(64)

#define SC 14336                   // nodes per chunk; bins = 57.3 KB LDS
#define CC 7                       // chunks / buckets (7*14336 = 100352 >= 100000)
#define CAP 925696                 // per-bucket capacity: mean 917504 + 8192 (~9 sigma)
#define BSEG_MAX 73                // segments per bucket in pass B -> grid 511 (~2 blocks/CU)

typedef unsigned long long u64;

// ---------------- Pass A: single edge scan -> per-chunk buckets ----------------
// Ballot-aggregated scatter: per wave, per 64-edge group, 7 ballots give each
// lane a dense rank; stores to run[b]+rank are CONSECUTIVE u64 slots ->
// coalesced. Zero LDS atomics; 7 global atomics per block; no register arrays
// with dynamic indices (no scratch spill).
__global__ __launch_bounds__(512) void scatter_kernel(
    const int* __restrict__ centers,
    const int* __restrict__ neighbors,
    const float* __restrict__ eng,
    const int* __restrict__ atom_type,
    const float* __restrict__ scales,
    u64* __restrict__ buckets,     // [CC][CAP]
    int* __restrict__ counters,    // [CC], pre-zeroed
    int E)
{
    __shared__ float s_scales[NUM_TYPES * NUM_TYPES];
    __shared__ int wave_cnt[8][CC];
    __shared__ int wave_base[8][CC];

    const int lane = threadIdx.x & 63;
    const int wave = threadIdx.x >> 6;

    if (threadIdx.x < NUM_TYPES * NUM_TYPES) s_scales[threadIdx.x] = scales[threadIdx.x];

    const int n4 = E >> 2;
    const int q_base = blockIdx.x * 2048 + threadIdx.x;
    const int4*   c4  = (const int4*)centers;
    const int4*   nb4 = (const int4*)neighbors;
    const float4* e4  = (const float4*)eng;

    const bool tail_wave = (blockIdx.x == 0) && (wave == 0);
    const int tail_i = (n4 << 2) + lane;

    // ---- pass 1: ballot-count per-wave bucket populations (centers only) ----
    int cnt[CC];
#pragma unroll
    for (int b = 0; b < CC; ++b) cnt[b] = 0;

#pragma unroll
    for (int k = 0; k < 4; ++k) {
        int q = q_base + k * 512;
        bool valid = q < n4;
        int qc = valid ? q : 0;
        int4 cc = c4[qc];
        int b0 = valid ? cc.x / SC : CC;
        int b1 = valid ? cc.y / SC : CC;
        int b2 = valid ? cc.z / SC : CC;
        int b3 = valid ? cc.w / SC : CC;
#pragma unroll
        for (int bb = 0; bb < CC; ++bb) {
            cnt[bb] += __popcll(__ballot(b0 == bb));
            cnt[bb] += __popcll(__ballot(b1 == bb));
            cnt[bb] += __popcll(__ballot(b2 == bb));
            cnt[bb] += __popcll(__ballot(b3 == bb));
        }
    }
    if (tail_wave) {  // E % 4 tail (dead for E = 6,400,000)
        bool valid = tail_i < E;
        int tb = valid ? centers[valid ? tail_i : 0] / SC : CC;
#pragma unroll
        for (int bb = 0; bb < CC; ++bb) cnt[bb] += __popcll(__ballot(tb == bb));
    }

    if (lane == 0) {
#pragma unroll
        for (int b = 0; b < CC; ++b) wave_cnt[wave][b] = cnt[b];
    }
    __syncthreads();

    // 7 threads: block totals -> one global atomic each -> per-wave bases
    if (threadIdx.x < CC) {
        int b = threadIdx.x;
        int tot = 0;
        int wc[8];
#pragma unroll
        for (int w = 0; w < 8; ++w) { wc[w] = wave_cnt[w][b]; tot += wc[w]; }
        int g = atomicAdd(&counters[b], tot);
#pragma unroll
        for (int w = 0; w < 8; ++w) { wave_base[w][b] = g; g += wc[w]; }
    }
    __syncthreads();

    // ---- pass 2: recompute (L1-hot), gather scales ONCE, coalesced append ----
    int run[CC];
#pragma unroll
    for (int b = 0; b < CC; ++b) run[b] = wave_base[wave][b];

#pragma unroll
    for (int k = 0; k < 4; ++k) {
        int q = q_base + k * 512;
        bool valid = q < n4;
        int qc = valid ? q : 0;
        int4   cc = c4[qc];
        int4   nn = nb4[qc];
        float4 ee = e4[qc];

        float v0 = ee.x * s_scales[atom_type[cc.x] * NUM_TYPES + atom_type[nn.x]] * FACTOR;
        float v1 = ee.y * s_scales[atom_type[cc.y] * NUM_TYPES + atom_type[nn.y]] * FACTOR;
        float v2 = ee.z * s_scales[atom_type[cc.z] * NUM_TYPES + atom_type[nn.z]] * FACTOR;
        float v3 = ee.w * s_scales[atom_type[cc.w] * NUM_TYPES + atom_type[nn.w]] * FACTOR;

        int b0 = valid ? cc.x / SC : CC;
        int b1 = valid ? cc.y / SC : CC;
        int b2 = valid ? cc.z / SC : CC;
        int b3 = valid ? cc.w / SC : CC;
        u64 p0 = ((u64)__float_as_uint(v0) << 32) | (unsigned)cc.x;
        u64 p1 = ((u64)__float_as_uint(v1) << 32) | (unsigned)cc.y;
        u64 p2 = ((u64)__float_as_uint(v2) << 32) | (unsigned)cc.z;
        u64 p3 = ((u64)__float_as_uint(v3) << 32) | (unsigned)cc.w;

        const u64 below = (1ull << lane) - 1;
#pragma unroll
        for (int bb = 0; bb < CC; ++bb) {
            u64 m0 = __ballot(b0 == bb);
            if (b0 == bb) buckets[(size_t)bb * CAP + run[bb] + __popcll(m0 & below)] = p0;
            run[bb] += __popcll(m0);
            u64 m1 = __ballot(b1 == bb);
            if (b1 == bb) buckets[(size_t)bb * CAP + run[bb] + __popcll(m1 & below)] = p1;
            run[bb] += __popcll(m1);
            u64 m2 = __ballot(b2 == bb);
            if (b2 == bb) buckets[(size_t)bb * CAP + run[bb] + __popcll(m2 & below)] = p2;
            run[bb] += __popcll(m2);
            u64 m3 = __ballot(b3 == bb);
            if (b3 == bb) buckets[(size_t)bb * CAP + run[bb] + __popcll(m3 & below)] = p3;
            run[bb] += __popcll(m3);
        }
    }
    if (tail_wave) {  // E % 4 tail, mirrored order from pass 1
        bool valid = tail_i < E;
        int ic = valid ? tail_i : 0;
        int ctr = centers[ic];
        float val = eng[ic] * s_scales[atom_type[ctr] * NUM_TYPES + atom_type[neighbors[ic]]] * FACTOR;
        int tb = valid ? ctr / SC : CC;
        u64 tp = ((u64)__float_as_uint(val) << 32) | (unsigned)ctr;
        const u64 below = (1ull << lane) - 1;
#pragma unroll
        for (int bb = 0; bb < CC; ++bb) {
            u64 m = __ballot(tb == bb);
            if (tb == bb) buckets[(size_t)bb * CAP + run[bb] + __popcll(m & below)] = tp;
            run[bb] += __popcll(m);
        }
    }
}

// ---------------- Pass B: bucket -> LDS bins -> partials (each edge read once) --
__global__ __launch_bounds__(512) void bucket_sum_kernel(
    const u64* __restrict__ buckets,
    const int* __restrict__ counters,
    float* __restrict__ partials,   // [CC][Bseg][SC]
    int Bseg)
{
    __shared__ float bins[SC];
    const int c = blockIdx.x % CC;
    const int s = blockIdx.x / CC;

    for (int j = threadIdx.x; j < SC; j += blockDim.x) bins[j] = 0.0f;
    __syncthreads();

    const int cnt = counters[c];
    const int base = c * SC;
    const u64* src = buckets + (size_t)c * CAP;

    for (int i = s * 512 + (int)threadIdx.x; i < cnt; i += Bseg * 512) {
        u64 p = src[i];
        int ctr = (int)(unsigned)p;
        float v = __uint_as_float((unsigned)(p >> 32));
        atomicAdd(&bins[ctr - base], v);
    }

    __syncthreads();
    float* dst = partials + ((size_t)c * Bseg + s) * SC;
    for (int j = threadIdx.x; j < SC; j += blockDim.x) dst[j] = bins[j];
}

// ---------------- Pass C: reduce partials -> out (float4) ----------------------
__global__ __launch_bounds__(256) void reduce_chunks_kernel(
    const float* __restrict__ partials, float* __restrict__ out, int Bseg)
{
    int t = blockIdx.x * blockDim.x + threadIdx.x;
    int n0 = t << 2;
    if (n0 >= N_NODES) return;
    int c = n0 / SC;
    int j = n0 - c * SC;
    const float* p = partials + (size_t)c * Bseg * SC + j;
    float4 sum = make_float4(0.f, 0.f, 0.f, 0.f);
    for (int s = 0; s < Bseg; ++s) {
        float4 v = *(const float4*)(p + (size_t)s * SC);
        sum.x += v.x; sum.y += v.y; sum.z += v.z; sum.w += v.w;
    }
    *(float4*)(out + n0) = sum;
}

// ---------------- Fallback tier 2: R3-style 7x chunk scan ----------------------
__global__ __launch_bounds__(512) void chunk_scan_kernel(
    const int* __restrict__ centers, const int* __restrict__ neighbors,
    const float* __restrict__ eng, const int* __restrict__ atom_type,
    const float* __restrict__ scales, float* __restrict__ ws, int E, int B)
{
    __shared__ float bins[SC];
    __shared__ float s_scales[NUM_TYPES * NUM_TYPES];
    const int c = blockIdx.x % CC;
    const int b = blockIdx.x / CC;
    if (threadIdx.x < NUM_TYPES * NUM_TYPES) s_scales[threadIdx.x] = scales[threadIdx.x];
    for (int j = threadIdx.x; j < SC; j += blockDim.x) bins[j] = 0.0f;
    __syncthreads();
    const int base = c * SC;
    const int n4 = E >> 2;
    for (int i = b * blockDim.x + threadIdx.x; i < n4; i += B * blockDim.x) {
        int4   cc = ((const int4*)centers)[i];
        int4   nn = ((const int4*)neighbors)[i];
        float4 e  = ((const float4*)eng)[i];
        unsigned j0 = (unsigned)(cc.x - base), j1 = (unsigned)(cc.y - base);
        unsigned j2 = (unsigned)(cc.z - base), j3 = (unsigned)(cc.w - base);
        if (j0 < SC) atomicAdd(&bins[j0], e.x * s_scales[atom_type[cc.x] * NUM_TYPES + atom_type[nn.x]] * FACTOR);
        if (j1 < SC) atomicAdd(&bins[j1], e.y * s_scales[atom_type[cc.y] * NUM_TYPES + atom_type[nn.y]] * FACTOR);
        if (j2 < SC) atomicAdd(&bins[j2], e.z * s_scales[atom_type[cc.z] * NUM_TYPES + atom_type[nn.z]] * FACTOR);
        if (j3 < SC) atomicAdd(&bins[j3], e.w * s_scales[atom_type[cc.w] * NUM_TYPES + atom_type[nn.w]] * FACTOR);
    }
    if (b == 0) {
        for (int i = (n4 << 2) + (int)threadIdx.x; i < E; i += blockDim.x) {
            int cn = centers[i];
            unsigned j = (unsigned)(cn - base);
            if (j < SC)
                atomicAdd(&bins[j], eng[i] * s_scales[atom_type[cn] * NUM_TYPES + atom_type[neighbors[i]]] * FACTOR);
        }
    }
    __syncthreads();
    float* dst = ws + ((size_t)c * B + b) * SC;
    for (int j = threadIdx.x; j < SC; j += blockDim.x) dst[j] = bins[j];
}

// ---------------- Fallback tier 3: direct atomics ------------------------------
__global__ __launch_bounds__(256) void edge_sum_atomic_kernel(
    const int* __restrict__ centers, const int* __restrict__ neighbors,
    const float* __restrict__ eng, const int* __restrict__ atom_type,
    const float* __restrict__ scales, float* __restrict__ out, int E)
{
    __shared__ float s_scales[NUM_TYPES * NUM_TYPES];
    if (threadIdx.x < NUM_TYPES * NUM_TYPES) s_scales[threadIdx.x] = scales[threadIdx.x];
    __syncthreads();
    int tid = blockIdx.x * blockDim.x + threadIdx.x;
    int stride = gridDim.x * blockDim.x;
    for (int i = tid; i < E; i += stride) {
        int cn = centers[i];
        float v = eng[i] * s_scales[atom_type[cn] * NUM_TYPES + atom_type[neighbors[i]]] * FACTOR;
        unsafeAtomicAdd(&out[cn], v);
    }
}

extern "C" void kernel_launch(void* const* d_in, const int* in_sizes, int n_in,
                              void* d_out, int out_size, void* d_ws, size_t ws_size,
                              hipStream_t stream) {
    const int E = in_sizes[1];
    const int* edge_index = (const int*)d_in[0];   // [2, E]
    const float* edge_eng = (const float*)d_in[1]; // [E, 1]
    const int* atom_type = (const int*)d_in[2];    // [N, 1]
    const float* scales = (const float*)d_in[3];   // [T, T]
    float* out = (float*)d_out;

    const int* centers = edge_index;
    const int* neighbors = edge_index + E;

    // ws layout (tier 1): [counters 256 B][buckets CC*CAP*8][partials CC*Bseg*SC*4]
    const size_t counters_bytes = 256;
    const size_t buckets_bytes = (size_t)CC * CAP * sizeof(u64);  // ~51.8 MB
    size_t fixed = counters_bytes + buckets_bytes;
    int Bseg = 0;
    if (ws_size > fixed)
        Bseg = (int)((ws_size - fixed) / ((size_t)CC * SC * sizeof(float)));
    if (Bseg > BSEG_MAX) Bseg = BSEG_MAX;

    if (Bseg >= 4) {
        int* counters = (int*)d_ws;
        u64* buckets = (u64*)((char*)d_ws + counters_bytes);
        float* partials = (float*)((char*)d_ws + fixed);

        hipMemsetAsync(counters, 0, CC * sizeof(int), stream);

        int n4 = E >> 2;
        int gridA = (n4 + 2047) / 2048;
        scatter_kernel<<<gridA, 512, 0, stream>>>(centers, neighbors, edge_eng,
                                                  atom_type, scales, buckets, counters, E);
        bucket_sum_kernel<<<CC * Bseg, 512, 0, stream>>>(buckets, counters, partials, Bseg);
        reduce_chunks_kernel<<<(N_NODES / 4 + 255) / 256, 256, 0, stream>>>(partials, out, Bseg);
        return;
    }

    // tier 2: R3-style chunk scan
    int B = (int)(ws_size / ((size_t)CC * SC * sizeof(float)));
    if (B > BSEG_MAX) B = BSEG_MAX;
    if (B >= 1) {
        float* partials = (float*)d_ws;
        chunk_scan_kernel<<<CC * B, 512, 0, stream>>>(centers, neighbors, edge_eng,
                                                      atom_type, scales, partials, E, B);
        reduce_chunks_kernel<<<(N_NODES / 4 + 255) / 256, 256, 0, stream>>>(partials, out, B);
        return;
    }

    // tier 3: direct atomics
    hipMemsetAsync(d_out, 0, (size_t)out_size * sizeof(float), stream);
    edge_sum_atomic_kernel<<<1024, 256, 0, stream>>>(centers, neighbors, edge_eng,
                                                     atom_type, scales, out, E);
}

// Round 7
// 229.592 us; speedup vs baseline: 1.1290x; 1.1290x over previous
//
#include <hip/hip_runtime.h>
#include <hip/hip_bf16.h>

#define N_NODES 100000
#define NUM_TYPES 8
#define FACTOR 0.125f  // 1/sqrt(64)

#define SC 14336                   // nodes per chunk; bins = 57.3 KB LDS
#define CC 7                       // chunks / buckets (7*14336 = 100352 >= 100000)
#define CAP 925696                 // per-bucket capacity: max-mean 917504 + 8192 (~8 sigma)
#define BSEG_MAX 73                // segments per bucket in pass B -> grid 511 (~2 blocks/CU)

typedef unsigned long long u64;

// ---------------- Pass A: SINGLE-pass ballot scatter ---------------------------
// 1 quad (4 edges) per thread. Fused count+rank: one 7-round ballot sequence
// yields wave-local ranks AND wave totals; packed values stay in registers
// across two __syncthreads (no re-read, no spill at ~45 VGPRs). 7 global
// atomics per block; stores are coalesced per-bucket bursts.
__global__ __launch_bounds__(512) void scatter_kernel(
    const int* __restrict__ centers,
    const int* __restrict__ neighbors,
    const float* __restrict__ eng,
    const int* __restrict__ atom_type,
    const float* __restrict__ scales,
    u64* __restrict__ buckets,     // [CC][CAP]
    int* __restrict__ counters,    // [CC], pre-zeroed
    int E)
{
    __shared__ float s_scales[NUM_TYPES * NUM_TYPES];
    __shared__ int wave_cnt[8][CC];
    __shared__ int wave_base[8][CC];

    const int lane = threadIdx.x & 63;
    const int wave = threadIdx.x >> 6;

    if (threadIdx.x < NUM_TYPES * NUM_TYPES) s_scales[threadIdx.x] = scales[threadIdx.x];
    __syncthreads();

    const int n4 = E >> 2;
    const int q = blockIdx.x * 512 + threadIdx.x;
    const bool valid = q < n4;
    const int qc = valid ? q : 0;

    int4   cc = ((const int4*)centers)[qc];
    int4   nn = ((const int4*)neighbors)[qc];
    float4 ee = ((const float4*)eng)[qc];

    float v0 = ee.x * s_scales[atom_type[cc.x] * NUM_TYPES + atom_type[nn.x]] * FACTOR;
    float v1 = ee.y * s_scales[atom_type[cc.y] * NUM_TYPES + atom_type[nn.y]] * FACTOR;
    float v2 = ee.z * s_scales[atom_type[cc.z] * NUM_TYPES + atom_type[nn.z]] * FACTOR;
    float v3 = ee.w * s_scales[atom_type[cc.w] * NUM_TYPES + atom_type[nn.w]] * FACTOR;

    const int b0 = valid ? cc.x / SC : CC;
    const int b1 = valid ? cc.y / SC : CC;
    const int b2 = valid ? cc.z / SC : CC;
    const int b3 = valid ? cc.w / SC : CC;
    u64 p0 = ((u64)__float_as_uint(v0) << 32) | (unsigned)cc.x;
    u64 p1 = ((u64)__float_as_uint(v1) << 32) | (unsigned)cc.y;
    u64 p2 = ((u64)__float_as_uint(v2) << 32) | (unsigned)cc.z;
    u64 p3 = ((u64)__float_as_uint(v3) << 32) | (unsigned)cc.w;

    // fused rank + count: wrun[bb] accumulates wave totals; r_j = wave-local rank
    int wrun[CC];
#pragma unroll
    for (int b = 0; b < CC; ++b) wrun[b] = 0;
    int r0 = 0, r1 = 0, r2 = 0, r3 = 0;
    const u64 below = (1ull << lane) - 1;

#pragma unroll
    for (int bb = 0; bb < CC; ++bb) {
        u64 m;
        m = __ballot(b0 == bb); if (b0 == bb) r0 = wrun[bb] + __popcll(m & below); wrun[bb] += __popcll(m);
        m = __ballot(b1 == bb); if (b1 == bb) r1 = wrun[bb] + __popcll(m & below); wrun[bb] += __popcll(m);
        m = __ballot(b2 == bb); if (b2 == bb) r2 = wrun[bb] + __popcll(m & below); wrun[bb] += __popcll(m);
        m = __ballot(b3 == bb); if (b3 == bb) r3 = wrun[bb] + __popcll(m & below); wrun[bb] += __popcll(m);
    }

    // E % 4 tail (dead for E = 6,400,000): block 0 wave 0 lanes handle it
    const bool tail_wave = (blockIdx.x == 0) && (wave == 0);
    bool t_valid = false; int tb = CC; int tr = 0; u64 tp = 0;
    if (tail_wave) {
        int ti = (n4 << 2) + lane;
        t_valid = ti < E;
        int tic = t_valid ? ti : 0;
        int ctr = centers[tic];
        float tv = eng[tic] * s_scales[atom_type[ctr] * NUM_TYPES + atom_type[neighbors[tic]]] * FACTOR;
        tb = t_valid ? ctr / SC : CC;
        tp = ((u64)__float_as_uint(tv) << 32) | (unsigned)ctr;
#pragma unroll
        for (int bb = 0; bb < CC; ++bb) {
            u64 m = __ballot(tb == bb);
            if (tb == bb) tr = wrun[bb] + __popcll(m & below);
            wrun[bb] += __popcll(m);
        }
    }

    if (lane == 0) {
#pragma unroll
        for (int b = 0; b < CC; ++b) wave_cnt[wave][b] = wrun[b];
    }
    __syncthreads();

    // 7 threads: block totals -> one global atomic each -> per-wave bases
    if (threadIdx.x < CC) {
        int b = threadIdx.x;
        int tot = 0;
        int wc[8];
#pragma unroll
        for (int w = 0; w < 8; ++w) { wc[w] = wave_cnt[w][b]; tot += wc[w]; }
        int g = atomicAdd(&counters[b], tot);
#pragma unroll
        for (int w = 0; w < 8; ++w) { wave_base[w][b] = g; g += wc[w]; }
    }
    __syncthreads();

    if (valid) {
        buckets[(size_t)b0 * CAP + wave_base[wave][b0] + r0] = p0;
        buckets[(size_t)b1 * CAP + wave_base[wave][b1] + r1] = p1;
        buckets[(size_t)b2 * CAP + wave_base[wave][b2] + r2] = p2;
        buckets[(size_t)b3 * CAP + wave_base[wave][b3] + r3] = p3;
    }
    if (t_valid) {
        buckets[(size_t)tb * CAP + wave_base[0][tb] + tr] = tp;
    }
}

// ---------------- Pass B: bucket -> LDS bins -> partials -----------------------
// 4 independent loads in flight per lane (latency hiding); coalesced u64 reads.
__global__ __launch_bounds__(512) void bucket_sum_kernel(
    const u64* __restrict__ buckets,
    const int* __restrict__ counters,
    float* __restrict__ partials,   // [CC][Bseg][SC]
    int Bseg)
{
    __shared__ float bins[SC];
    const int c = blockIdx.x % CC;
    const int s = blockIdx.x / CC;

    for (int j = threadIdx.x; j < SC; j += blockDim.x) bins[j] = 0.0f;
    __syncthreads();

    const int cnt = counters[c];
    const int base = c * SC;
    const u64* src = buckets + (size_t)c * CAP;
    const int st = Bseg * 512;

    int i = s * 512 + (int)threadIdx.x;
    for (; i + 3 * st < cnt; i += 4 * st) {
        u64 a = src[i];
        u64 b = src[i + st];
        u64 d = src[i + 2 * st];
        u64 e = src[i + 3 * st];
        atomicAdd(&bins[(int)(unsigned)a - base], __uint_as_float((unsigned)(a >> 32)));
        atomicAdd(&bins[(int)(unsigned)b - base], __uint_as_float((unsigned)(b >> 32)));
        atomicAdd(&bins[(int)(unsigned)d - base], __uint_as_float((unsigned)(d >> 32)));
        atomicAdd(&bins[(int)(unsigned)e - base], __uint_as_float((unsigned)(e >> 32)));
    }
    for (; i < cnt; i += st) {
        u64 p = src[i];
        atomicAdd(&bins[(int)(unsigned)p - base], __uint_as_float((unsigned)(p >> 32)));
    }

    __syncthreads();
    float* dst = partials + ((size_t)c * Bseg + s) * SC;
    for (int j = threadIdx.x; j < SC; j += blockDim.x) dst[j] = bins[j];
}

// ---------------- Pass C: reduce partials -> out (float4) ----------------------
__global__ __launch_bounds__(256) void reduce_chunks_kernel(
    const float* __restrict__ partials, float* __restrict__ out, int Bseg)
{
    int t = blockIdx.x * blockDim.x + threadIdx.x;
    int n0 = t << 2;
    if (n0 >= N_NODES) return;
    int c = n0 / SC;
    int j = n0 - c * SC;
    const float* p = partials + (size_t)c * Bseg * SC + j;
    float4 sum = make_float4(0.f, 0.f, 0.f, 0.f);
    for (int s = 0; s < Bseg; ++s) {
        float4 v = *(const float4*)(p + (size_t)s * SC);
        sum.x += v.x; sum.y += v.y; sum.z += v.z; sum.w += v.w;
    }
    *(float4*)(out + n0) = sum;
}

// ---------------- Fallback tier 2: R3-style 7x chunk scan ----------------------
__global__ __launch_bounds__(512) void chunk_scan_kernel(
    const int* __restrict__ centers, const int* __restrict__ neighbors,
    const float* __restrict__ eng, const int* __restrict__ atom_type,
    const float* __restrict__ scales, float* __restrict__ ws, int E, int B)
{
    __shared__ float bins[SC];
    __shared__ float s_scales[NUM_TYPES * NUM_TYPES];
    const int c = blockIdx.x % CC;
    const int b = blockIdx.x / CC;
    if (threadIdx.x < NUM_TYPES * NUM_TYPES) s_scales[threadIdx.x] = scales[threadIdx.x];
    for (int j = threadIdx.x; j < SC; j += blockDim.x) bins[j] = 0.0f;
    __syncthreads();
    const int base = c * SC;
    const int n4 = E >> 2;
    for (int i = b * blockDim.x + threadIdx.x; i < n4; i += B * blockDim.x) {
        int4   cc = ((const int4*)centers)[i];
        int4   nn = ((const int4*)neighbors)[i];
        float4 e  = ((const float4*)eng)[i];
        unsigned j0 = (unsigned)(cc.x - base), j1 = (unsigned)(cc.y - base);
        unsigned j2 = (unsigned)(cc.z - base), j3 = (unsigned)(cc.w - base);
        if (j0 < SC) atomicAdd(&bins[j0], e.x * s_scales[atom_type[cc.x] * NUM_TYPES + atom_type[nn.x]] * FACTOR);
        if (j1 < SC) atomicAdd(&bins[j1], e.y * s_scales[atom_type[cc.y] * NUM_TYPES + atom_type[nn.y]] * FACTOR);
        if (j2 < SC) atomicAdd(&bins[j2], e.z * s_scales[atom_type[cc.z] * NUM_TYPES + atom_type[nn.z]] * FACTOR);
        if (j3 < SC) atomicAdd(&bins[j3], e.w * s_scales[atom_type[cc.w] * NUM_TYPES + atom_type[nn.w]] * FACTOR);
    }
    if (b == 0) {
        for (int i = (n4 << 2) + (int)threadIdx.x; i < E; i += blockDim.x) {
            int cn = centers[i];
            unsigned j = (unsigned)(cn - base);
            if (j < SC)
                atomicAdd(&bins[j], eng[i] * s_scales[atom_type[cn] * NUM_TYPES + atom_type[neighbors[i]]] * FACTOR);
        }
    }
    __syncthreads();
    float* dst = ws + ((size_t)c * B + b) * SC;
    for (int j = threadIdx.x; j < SC; j += blockDim.x) dst[j] = bins[j];
}

// ---------------- Fallback tier 3: direct atomics ------------------------------
__global__ __launch_bounds__(256) void edge_sum_atomic_kernel(
    const int* __restrict__ centers, const int* __restrict__ neighbors,
    const float* __restrict__ eng, const int* __restrict__ atom_type,
    const float* __restrict__ scales, float* __restrict__ out, int E)
{
    __shared__ float s_scales[NUM_TYPES * NUM_TYPES];
    if (threadIdx.x < NUM_TYPES * NUM_TYPES) s_scales[threadIdx.x] = scales[threadIdx.x];
    __syncthreads();
    int tid = blockIdx.x * blockDim.x + threadIdx.x;
    int stride = gridDim.x * blockDim.x;
    for (int i = tid; i < E; i += stride) {
        int cn = centers[i];
        float v = eng[i] * s_scales[atom_type[cn] * NUM_TYPES + atom_type[neighbors[i]]] * FACTOR;
        unsafeAtomicAdd(&out[cn], v);
    }
}

extern "C" void kernel_launch(void* const* d_in, const int* in_sizes, int n_in,
                              void* d_out, int out_size, void* d_ws, size_t ws_size,
                              hipStream_t stream) {
    const int E = in_sizes[1];
    const int* edge_index = (const int*)d_in[0];   // [2, E]
    const float* edge_eng = (const float*)d_in[1]; // [E, 1]
    const int* atom_type = (const int*)d_in[2];    // [N, 1]
    const float* scales = (const float*)d_in[3];   // [T, T]
    float* out = (float*)d_out;

    const int* centers = edge_index;
    const int* neighbors = edge_index + E;

    // ws layout (tier 1): [counters 256 B][buckets CC*CAP*8][partials CC*Bseg*SC*4]
    const size_t counters_bytes = 256;
    const size_t buckets_bytes = (size_t)CC * CAP * sizeof(u64);  // ~51.8 MB
    size_t fixed = counters_bytes + buckets_bytes;
    int Bseg = 0;
    if (ws_size > fixed)
        Bseg = (int)((ws_size - fixed) / ((size_t)CC * SC * sizeof(float)));
    if (Bseg > BSEG_MAX) Bseg = BSEG_MAX;

    if (Bseg >= 4) {
        int* counters = (int*)d_ws;
        u64* buckets = (u64*)((char*)d_ws + counters_bytes);
        float* partials = (float*)((char*)d_ws + fixed);

        hipMemsetAsync(counters, 0, CC * sizeof(int), stream);

        int n4 = E >> 2;
        int gridA = (n4 + 511) / 512;   // 1 quad per thread
        scatter_kernel<<<gridA, 512, 0, stream>>>(centers, neighbors, edge_eng,
                                                  atom_type, scales, buckets, counters, E);
        bucket_sum_kernel<<<CC * Bseg, 512, 0, stream>>>(buckets, counters, partials, Bseg);
        reduce_chunks_kernel<<<(N_NODES / 4 + 255) / 256, 256, 0, stream>>>(partials, out, Bseg);
        return;
    }

    // tier 2: R3-style chunk scan
    int B = (int)(ws_size / ((size_t)CC * SC * sizeof(float)));
    if (B > BSEG_MAX) B = BSEG_MAX;
    if (B >= 1) {
        float* partials = (float*)d_ws;
        chunk_scan_kernel<<<CC * B, 512, 0, stream>>>(centers, neighbors, edge_eng,
                                                      atom_type, scales, partials, E, B);
        reduce_chunks_kernel<<<(N_NODES / 4 + 255) / 256, 256, 0, stream>>>(partials, out, B);
        return;
    }

    // tier 3: direct atomics
    hipMemsetAsync(d_out, 0, (size_t)out_size * sizeof(float), stream);
    edge_sum_atomic_kernel<<<1024, 256, 0, stream>>>(centers, neighbors, edge_eng,
                                                     atom_type, scales, out, E);
}

// Round 8
// 223.916 us; speedup vs baseline: 1.1576x; 1.0253x over previous
//
#include <hip/hip_runtime.h>
#include <hip/hip_bf16.h>

#define N_NODES 100000
#define NUM_TYPES 8
#define FACTOR 0.125f  // 1/sqrt(64)

#define SC 14336                   // nodes per chunk; bins = 57.3 KB LDS
#define CC 7                       // chunks / buckets (7*14336 = 100352 >= 100000)
#define CAP 925696                 // per-bucket capacity: max-mean 917504 + 8192 (~8 sigma)
#define BSEG_MAX 73                // segments per bucket in pass B -> grid 511 (~2 blocks/CU)
#define CTR_STRIDE 32              // counters padded to 128 B: one cacheline per counter

typedef unsigned long long u64;

// ---------------- Pass A: SINGLE-pass ballot scatter ---------------------------
// 1 quad (4 edges) per thread. Fused count+rank ballots; packed values stay in
// registers across the two __syncthreads. 7 global atomics per block, EACH ON
// ITS OWN CACHELINE (CTR_STRIDE) — R6's counters shared one line, serializing
// 21,875 device-scope RMWs (~100 us): that was the scatter wall.
__global__ __launch_bounds__(512) void scatter_kernel(
    const int* __restrict__ centers,
    const int* __restrict__ neighbors,
    const float* __restrict__ eng,
    const int* __restrict__ atom_type,
    const float* __restrict__ scales,
    u64* __restrict__ buckets,     // [CC][CAP]
    int* __restrict__ counters,    // [CC*CTR_STRIDE], pre-zeroed
    int E)
{
    __shared__ float s_scales[NUM_TYPES * NUM_TYPES];
    __shared__ int wave_cnt[8][CC];
    __shared__ int wave_base[8][CC];

    const int lane = threadIdx.x & 63;
    const int wave = threadIdx.x >> 6;

    if (threadIdx.x < NUM_TYPES * NUM_TYPES) s_scales[threadIdx.x] = scales[threadIdx.x];
    __syncthreads();

    const int n4 = E >> 2;
    const int q = blockIdx.x * 512 + threadIdx.x;
    const bool valid = q < n4;
    const int qc = valid ? q : 0;

    int4   cc = ((const int4*)centers)[qc];
    int4   nn = ((const int4*)neighbors)[qc];
    float4 ee = ((const float4*)eng)[qc];

    float v0 = ee.x * s_scales[atom_type[cc.x] * NUM_TYPES + atom_type[nn.x]] * FACTOR;
    float v1 = ee.y * s_scales[atom_type[cc.y] * NUM_TYPES + atom_type[nn.y]] * FACTOR;
    float v2 = ee.z * s_scales[atom_type[cc.z] * NUM_TYPES + atom_type[nn.z]] * FACTOR;
    float v3 = ee.w * s_scales[atom_type[cc.w] * NUM_TYPES + atom_type[nn.w]] * FACTOR;

    const int b0 = valid ? cc.x / SC : CC;
    const int b1 = valid ? cc.y / SC : CC;
    const int b2 = valid ? cc.z / SC : CC;
    const int b3 = valid ? cc.w / SC : CC;
    u64 p0 = ((u64)__float_as_uint(v0) << 32) | (unsigned)cc.x;
    u64 p1 = ((u64)__float_as_uint(v1) << 32) | (unsigned)cc.y;
    u64 p2 = ((u64)__float_as_uint(v2) << 32) | (unsigned)cc.z;
    u64 p3 = ((u64)__float_as_uint(v3) << 32) | (unsigned)cc.w;

    // fused rank + count
    int wrun[CC];
#pragma unroll
    for (int b = 0; b < CC; ++b) wrun[b] = 0;
    int r0 = 0, r1 = 0, r2 = 0, r3 = 0;
    const u64 below = (1ull << lane) - 1;

#pragma unroll
    for (int bb = 0; bb < CC; ++bb) {
        u64 m;
        m = __ballot(b0 == bb); if (b0 == bb) r0 = wrun[bb] + __popcll(m & below); wrun[bb] += __popcll(m);
        m = __ballot(b1 == bb); if (b1 == bb) r1 = wrun[bb] + __popcll(m & below); wrun[bb] += __popcll(m);
        m = __ballot(b2 == bb); if (b2 == bb) r2 = wrun[bb] + __popcll(m & below); wrun[bb] += __popcll(m);
        m = __ballot(b3 == bb); if (b3 == bb) r3 = wrun[bb] + __popcll(m & below); wrun[bb] += __popcll(m);
    }

    // E % 4 tail (dead for E = 6,400,000): block 0 wave 0 lanes handle it
    const bool tail_wave = (blockIdx.x == 0) && (wave == 0);
    bool t_valid = false; int tb = CC; int tr = 0; u64 tp = 0;
    if (tail_wave) {
        int ti = (n4 << 2) + lane;
        t_valid = ti < E;
        int tic = t_valid ? ti : 0;
        int ctr = centers[tic];
        float tv = eng[tic] * s_scales[atom_type[ctr] * NUM_TYPES + atom_type[neighbors[tic]]] * FACTOR;
        tb = t_valid ? ctr / SC : CC;
        tp = ((u64)__float_as_uint(tv) << 32) | (unsigned)ctr;
#pragma unroll
        for (int bb = 0; bb < CC; ++bb) {
            u64 m = __ballot(tb == bb);
            if (tb == bb) tr = wrun[bb] + __popcll(m & below);
            wrun[bb] += __popcll(m);
        }
    }

    if (lane == 0) {
#pragma unroll
        for (int b = 0; b < CC; ++b) wave_cnt[wave][b] = wrun[b];
    }
    __syncthreads();

    // 7 threads: block totals -> one global atomic each (separate cachelines)
    if (threadIdx.x < CC) {
        int b = threadIdx.x;
        int tot = 0;
        int wc[8];
#pragma unroll
        for (int w = 0; w < 8; ++w) { wc[w] = wave_cnt[w][b]; tot += wc[w]; }
        int g = atomicAdd(&counters[b * CTR_STRIDE], tot);
#pragma unroll
        for (int w = 0; w < 8; ++w) { wave_base[w][b] = g; g += wc[w]; }
    }
    __syncthreads();

    if (valid) {
        buckets[(size_t)b0 * CAP + wave_base[wave][b0] + r0] = p0;
        buckets[(size_t)b1 * CAP + wave_base[wave][b1] + r1] = p1;
        buckets[(size_t)b2 * CAP + wave_base[wave][b2] + r2] = p2;
        buckets[(size_t)b3 * CAP + wave_base[wave][b3] + r3] = p3;
    }
    if (t_valid) {
        buckets[(size_t)tb * CAP + wave_base[0][tb] + tr] = tp;
    }
}

// ---------------- Pass B: bucket -> LDS bins -> partials -----------------------
__global__ __launch_bounds__(512) void bucket_sum_kernel(
    const u64* __restrict__ buckets,
    const int* __restrict__ counters,   // padded by CTR_STRIDE
    float* __restrict__ partials,       // [CC][Bseg][SC]
    int Bseg)
{
    __shared__ float bins[SC];
    const int c = blockIdx.x % CC;
    const int s = blockIdx.x / CC;

    for (int j = threadIdx.x; j < SC; j += blockDim.x) bins[j] = 0.0f;
    __syncthreads();

    const int cnt = counters[c * CTR_STRIDE];
    const int base = c * SC;
    const u64* src = buckets + (size_t)c * CAP;
    const int st = Bseg * 512;

    int i = s * 512 + (int)threadIdx.x;
    for (; i + 3 * st < cnt; i += 4 * st) {
        u64 a = src[i];
        u64 b = src[i + st];
        u64 d = src[i + 2 * st];
        u64 e = src[i + 3 * st];
        atomicAdd(&bins[(int)(unsigned)a - base], __uint_as_float((unsigned)(a >> 32)));
        atomicAdd(&bins[(int)(unsigned)b - base], __uint_as_float((unsigned)(b >> 32)));
        atomicAdd(&bins[(int)(unsigned)d - base], __uint_as_float((unsigned)(d >> 32)));
        atomicAdd(&bins[(int)(unsigned)e - base], __uint_as_float((unsigned)(e >> 32)));
    }
    for (; i < cnt; i += st) {
        u64 p = src[i];
        atomicAdd(&bins[(int)(unsigned)p - base], __uint_as_float((unsigned)(p >> 32)));
    }

    __syncthreads();
    float* dst = partials + ((size_t)c * Bseg + s) * SC;
    for (int j = threadIdx.x; j < SC; j += blockDim.x) dst[j] = bins[j];
}

// ---------------- Pass C: reduce partials -> out (float4) ----------------------
__global__ __launch_bounds__(256) void reduce_chunks_kernel(
    const float* __restrict__ partials, float* __restrict__ out, int Bseg)
{
    int t = blockIdx.x * blockDim.x + threadIdx.x;
    int n0 = t << 2;
    if (n0 >= N_NODES) return;
    int c = n0 / SC;
    int j = n0 - c * SC;
    const float* p = partials + (size_t)c * Bseg * SC + j;
    float4 sum = make_float4(0.f, 0.f, 0.f, 0.f);
    for (int s = 0; s < Bseg; ++s) {
        float4 v = *(const float4*)(p + (size_t)s * SC);
        sum.x += v.x; sum.y += v.y; sum.z += v.z; sum.w += v.w;
    }
    *(float4*)(out + n0) = sum;
}

// ---------------- Fallback tier 2: R3-style 7x chunk scan ----------------------
__global__ __launch_bounds__(512) void chunk_scan_kernel(
    const int* __restrict__ centers, const int* __restrict__ neighbors,
    const float* __restrict__ eng, const int* __restrict__ atom_type,
    const float* __restrict__ scales, float* __restrict__ ws, int E, int B)
{
    __shared__ float bins[SC];
    __shared__ float s_scales[NUM_TYPES * NUM_TYPES];
    const int c = blockIdx.x % CC;
    const int b = blockIdx.x / CC;
    if (threadIdx.x < NUM_TYPES * NUM_TYPES) s_scales[threadIdx.x] = scales[threadIdx.x];
    for (int j = threadIdx.x; j < SC; j += blockDim.x) bins[j] = 0.0f;
    __syncthreads();
    const int base = c * SC;
    const int n4 = E >> 2;
    for (int i = b * blockDim.x + threadIdx.x; i < n4; i += B * blockDim.x) {
        int4   cc = ((const int4*)centers)[i];
        int4   nn = ((const int4*)neighbors)[i];
        float4 e  = ((const float4*)eng)[i];
        unsigned j0 = (unsigned)(cc.x - base), j1 = (unsigned)(cc.y - base);
        unsigned j2 = (unsigned)(cc.z - base), j3 = (unsigned)(cc.w - base);
        if (j0 < SC) atomicAdd(&bins[j0], e.x * s_scales[atom_type[cc.x] * NUM_TYPES + atom_type[nn.x]] * FACTOR);
        if (j1 < SC) atomicAdd(&bins[j1], e.y * s_scales[atom_type[cc.y] * NUM_TYPES + atom_type[nn.y]] * FACTOR);
        if (j2 < SC) atomicAdd(&bins[j2], e.z * s_scales[atom_type[cc.z] * NUM_TYPES + atom_type[nn.z]] * FACTOR);
        if (j3 < SC) atomicAdd(&bins[j3], e.w * s_scales[atom_type[cc.w] * NUM_TYPES + atom_type[nn.w]] * FACTOR);
    }
    if (b == 0) {
        for (int i = (n4 << 2) + (int)threadIdx.x; i < E; i += blockDim.x) {
            int cn = centers[i];
            unsigned j = (unsigned)(cn - base);
            if (j < SC)
                atomicAdd(&bins[j], eng[i] * s_scales[atom_type[cn] * NUM_TYPES + atom_type[neighbors[i]]] * FACTOR);
        }
    }
    __syncthreads();
    float* dst = ws + ((size_t)c * B + b) * SC;
    for (int j = threadIdx.x; j < SC; j += blockDim.x) dst[j] = bins[j];
}

// ---------------- Fallback tier 3: direct atomics ------------------------------
__global__ __launch_bounds__(256) void edge_sum_atomic_kernel(
    const int* __restrict__ centers, const int* __restrict__ neighbors,
    const float* __restrict__ eng, const int* __restrict__ atom_type,
    const float* __restrict__ scales, float* __restrict__ out, int E)
{
    __shared__ float s_scales[NUM_TYPES * NUM_TYPES];
    if (threadIdx.x < NUM_TYPES * NUM_TYPES) s_scales[threadIdx.x] = scales[threadIdx.x];
    __syncthreads();
    int tid = blockIdx.x * blockDim.x + threadIdx.x;
    int stride = gridDim.x * blockDim.x;
    for (int i = tid; i < E; i += stride) {
        int cn = centers[i];
        float v = eng[i] * s_scales[atom_type[cn] * NUM_TYPES + atom_type[neighbors[i]]] * FACTOR;
        unsafeAtomicAdd(&out[cn], v);
    }
}

extern "C" void kernel_launch(void* const* d_in, const int* in_sizes, int n_in,
                              void* d_out, int out_size, void* d_ws, size_t ws_size,
                              hipStream_t stream) {
    const int E = in_sizes[1];
    const int* edge_index = (const int*)d_in[0];   // [2, E]
    const float* edge_eng = (const float*)d_in[1]; // [E, 1]
    const int* atom_type = (const int*)d_in[2];    // [N, 1]
    const float* scales = (const float*)d_in[3];   // [T, T]
    float* out = (float*)d_out;

    const int* centers = edge_index;
    const int* neighbors = edge_index + E;

    // ws layout (tier 1): [counters CC*CTR_STRIDE ints, 1 KB][buckets CC*CAP*8][partials]
    const size_t counters_bytes = 1024;
    const size_t buckets_bytes = (size_t)CC * CAP * sizeof(u64);  // ~51.8 MB
    size_t fixed = counters_bytes + buckets_bytes;
    int Bseg = 0;
    if (ws_size > fixed)
        Bseg = (int)((ws_size - fixed) / ((size_t)CC * SC * sizeof(float)));
    if (Bseg > BSEG_MAX) Bseg = BSEG_MAX;

    if (Bseg >= 4) {
        int* counters = (int*)d_ws;
        u64* buckets = (u64*)((char*)d_ws + counters_bytes);
        float* partials = (float*)((char*)d_ws + fixed);

        hipMemsetAsync(counters, 0, CC * CTR_STRIDE * sizeof(int), stream);

        int n4 = E >> 2;
        int gridA = (n4 + 511) / 512;   // 1 quad per thread
        scatter_kernel<<<gridA, 512, 0, stream>>>(centers, neighbors, edge_eng,
                                                  atom_type, scales, buckets, counters, E);
        bucket_sum_kernel<<<CC * Bseg, 512, 0, stream>>>(buckets, counters, partials, Bseg);
        reduce_chunks_kernel<<<(N_NODES / 4 + 255) / 256, 256, 0, stream>>>(partials, out, Bseg);
        return;
    }

    // tier 2: R3-style chunk scan
    int B = (int)(ws_size / ((size_t)CC * SC * sizeof(float)));
    if (B > BSEG_MAX) B = BSEG_MAX;
    if (B >= 1) {
        float* partials = (float*)d_ws;
        chunk_scan_kernel<<<CC * B, 512, 0, stream>>>(centers, neighbors, edge_eng,
                                                      atom_type, scales, partials, E, B);
        reduce_chunks_kernel<<<(N_NODES / 4 + 255) / 256, 256, 0, stream>>>(partials, out, B);
        return;
    }

    // tier 3: direct atomics
    hipMemsetAsync(d_out, 0, (size_t)out_size * sizeof(float), stream);
    edge_sum_atomic_kernel<<<1024, 256, 0, stream>>>(centers, neighbors, edge_eng,
                                                     atom_type, scales, out, E);
}